// Round 1
// baseline (99.345 us; speedup 1.0000x reference)
//
#include <hip/hip_runtime.h>

#define NDIM 28
#define SPAT 784            // 28*28
#define STRIPS 196          // 784/4 float4 strips per plane
#define PADR 30
#define PADC 32
#define NB 256
#define CIN 256
#define COUT 256

// Kernel 1: xs[b] = sum_c x[b,c], written as padded+halo'd xsp[b][30][32]
// so that kernel 2 needs no modular indexing and all loads are float4-aligned.
__global__ __launch_bounds__(64) void k_sum(const float* __restrict__ x,
                                            float* __restrict__ xsp) {
    int tid = blockIdx.x * 64 + threadIdx.x;   // 784 blocks * 64 = 256*196
    int b = tid / STRIPS;
    int s = tid % STRIPS;
    int i = s / 7;          // row 0..27
    int q = s % 7;          // float4 quad 0..6 (cols 4q..4q+3)

    const float4* xp = (const float4*)x + (size_t)b * (CIN * STRIPS) + s;
    float ax = 0.f, ay = 0.f, az = 0.f, aw = 0.f;
    #pragma unroll 16
    for (int c = 0; c < CIN; ++c) {
        float4 v = xp[c * STRIPS];
        ax += v.x; ay += v.y; az += v.z; aw += v.w;
    }
    float4 acc = {ax, ay, az, aw};

    float* base = xsp + (size_t)b * (PADR * PADC);
    *(float4*)(base + i * PADC + q * 4) = acc;
    if (q == 0)  // col halo: cols 28,29 replicate cols 0,1 (30,31 junk-unused)
        *(float4*)(base + i * PADC + 28) = acc;
    if (i < 2) { // row halo: rows 28,29 replicate rows 0,1
        *(float4*)(base + (i + 28) * PADC + q * 4) = acc;
        if (q == 0)
            *(float4*)(base + (i + 28) * PADC + 28) = acc;
    }
}

// Kernel 2: out[b,co,i,j] = sum_{a,c} w0[co,2-a,2-c] * xsp[b,i+a,js+j+c]
// One thread owns one float4 output strip for ALL 16 co of its group:
// window loaded once into registers, reused 16x.
__global__ __launch_bounds__(256) void k_conv(const float* __restrict__ xsp,
                                              const float* __restrict__ w,
                                              float* __restrict__ out) {
    int b  = blockIdx.x >> 4;   // 0..255
    int cg = blockIdx.x & 15;   // co group: 16 co each
    int t  = threadIdx.x;
    if (t >= STRIPS) return;

    int i  = t / 7;
    int js = (t % 7) * 4;

    const float* bp = xsp + (size_t)b * (PADR * PADC);
    float W[3][8];
    #pragma unroll
    for (int a = 0; a < 3; ++a) {
        float4 lo = *(const float4*)(bp + (i + a) * PADC + js);
        float4 hi = *(const float4*)(bp + (i + a) * PADC + js + 4);
        W[a][0] = lo.x; W[a][1] = lo.y; W[a][2] = lo.z; W[a][3] = lo.w;
        W[a][4] = hi.x; W[a][5] = hi.y; W[a][6] = hi.z; W[a][7] = hi.w;
    }

    size_t out_base = ((size_t)b * COUT + (size_t)cg * 16) * SPAT + i * NDIM + js;

    for (int cl = 0; cl < 16; ++cl) {
        int co = cg * 16 + cl;
        const float* wp = w + (size_t)co * (CIN * 9);  // kernel[co, 0, :, :]
        float f[3][3];
        #pragma unroll
        for (int a = 0; a < 3; ++a)
            #pragma unroll
            for (int c = 0; c < 3; ++c)
                f[a][c] = wp[(2 - a) * 3 + (2 - c)];

        float o0 = 0.f, o1 = 0.f, o2 = 0.f, o3 = 0.f;
        #pragma unroll
        for (int a = 0; a < 3; ++a) {
            #pragma unroll
            for (int c = 0; c < 3; ++c) {
                float fv = f[a][c];
                o0 += fv * W[a][0 + c];
                o1 += fv * W[a][1 + c];
                o2 += fv * W[a][2 + c];
                o3 += fv * W[a][3 + c];
            }
        }
        float4 o = {o0, o1, o2, o3};
        *(float4*)(out + out_base + (size_t)cl * SPAT) = o;
    }
}

extern "C" void kernel_launch(void* const* d_in, const int* in_sizes, int n_in,
                              void* d_out, int out_size, void* d_ws, size_t ws_size,
                              hipStream_t stream) {
    const float* x = (const float*)d_in[0];       // (256,256,28,28) f32
    const float* w = (const float*)d_in[1];       // (256,256,3,3) f32
    float* out = (float*)d_out;                   // (256,256,28,28) f32
    float* xsp = (float*)d_ws;                    // 256*30*32 f32 = 983 KB

    k_sum<<<SPAT, 64, 0, stream>>>(x, xsp);               // 784 blocks
    k_conv<<<NB * 16, 256, 0, stream>>>(xsp, w, out);     // 4096 blocks
}